// Round 16
// baseline (374.408 us; speedup 1.0000x reference)
//
#include <hip/hip_runtime.h>
#include <math.h>

// b=4,n=2048 -> 8192 rows; d=1024; h=8; e=16; cs=2048. Output int32 [8192,8].
// argmax_c q.cbn_c == argmax_c ((x.W - mu*colsum(W)) . cbn_c). Codebook fp64-
// normalized. bf16 3-split MFMA path (verified R7/R10/R14): v = h+m+l (8+8+8
// mantissa bits, fp32 exponent range); v_p*v_c ~= hh + hm+mh + hl+mm+lh via 3
// quad-packed K=32 bf16 MFMAs. Frag-major B layouts (R9/R10). R14: x staged
// row-dense into LDS. R16: single kernel, phases separated by a MANUAL
// device-scope grid barrier (R15's hipLaunchCooperativeKernel never launched
// -- absmax 2048 = untouched output). Co-residency by construction: 66.9KB
// LDS -> exactly 2 blocks/CU x 256 CU = 512 = grid; launch_bounds(512,4)
// pins <=128 VGPR -> 16 waves/CU = 2 blocks. Barrier flags zeroed per call
// via hipMemsetAsync (graph-legal memset node).

typedef short bf16x8 __attribute__((ext_vector_type(8)));
typedef float f32x4 __attribute__((ext_vector_type(4)));

__device__ __forceinline__ void stage16(const float* g, float* lds_base) {
  __builtin_amdgcn_global_load_lds(
      (const __attribute__((address_space(1))) void*)g,
      (__attribute__((address_space(3))) void*)lds_base, 16, 0, 0);
}

__device__ __forceinline__ unsigned short f2bf(float f) {
  unsigned u = __builtin_bit_cast(unsigned, f);
  unsigned r = (u + 0x7FFFu + ((u >> 16) & 1u)) >> 16;   // RNE
  return (unsigned short)r;
}
__device__ __forceinline__ float bf2f(unsigned short b) {
  return __builtin_bit_cast(float, (unsigned)b << 16);
}
__device__ __forceinline__ void split3(float v, unsigned short& h,
                                       unsigned short& m, unsigned short& l) {
  h = f2bf(v);
  float r = v - bf2f(h);
  m = f2bf(r);
  float r2 = r - bf2f(m);
  l = f2bf(r2);
}

// single-use device-scope grid barrier (cnt/flag pre-zeroed each launch)
__device__ __forceinline__ void gbar(unsigned* cnt, unsigned* flag,
                                     unsigned nb) {
  __syncthreads();
  if (threadIdx.x == 0) {
    __threadfence();   // release: prior writes visible device-wide
    unsigned prev = __hip_atomic_fetch_add(cnt, 1u, __ATOMIC_ACQ_REL,
                                           __HIP_MEMORY_SCOPE_AGENT);
    if (prev == nb - 1) {
      __hip_atomic_store(flag, 1u, __ATOMIC_RELEASE,
                         __HIP_MEMORY_SCOPE_AGENT);
    } else {
      while (__hip_atomic_load(flag, __ATOMIC_ACQUIRE,
                               __HIP_MEMORY_SCOPE_AGENT) == 0u)
        __builtin_amdgcn_s_sleep(1);
    }
    __threadfence();   // acquire
  }
  __syncthreads();
}

__global__ __launch_bounds__(512, 4) void k_all(
    const float* __restrict__ x, const float* __restrict__ W,
    const float* __restrict__ cb, int* __restrict__ out,
    float* __restrict__ csum, float* __restrict__ amv, int* __restrict__ ami,
    unsigned short* __restrict__ wfrag, unsigned short* __restrict__ cfrag,
    unsigned short* __restrict__ ph, unsigned short* __restrict__ pm,
    unsigned short* __restrict__ pl, unsigned* __restrict__ bar) {
  __shared__ __align__(16) float smemF[16 * 1028];   // 65792 B (multi-use)
  __shared__ float sPs[8][2][16];
  __shared__ float sMu[16];

  const int bid = blockIdx.x;          // 0..511
  const int t = threadIdx.x;           // 0..511
  const int tid = bid * 512 + t;       // 0..262143
  const int lane = t & 63, w = t >> 6; // wave 0..7
  const int q = lane >> 4, n16 = lane & 15, oct = q & 1;
  const bool qlt2 = (q < 2);
  const int p1 = qlt2 ? 0 : 1, p2 = qlt2 ? 1 : 0, p3 = qlt2 ? 2 : 0;

  // ================= Phase A: prep (cbnorm | wsplit | colsum) ==============
  if (tid < 131072 && (tid & 7) == 0) {   // cbnorm item v = tid>>3 (0..16383)
    int v = tid >> 3;
    int hh = v >> 11, c = v & 2047, tl = c >> 4, n = c & 15;
    const float4* p = (const float4*)(cb + (size_t)v * 16);
    float4 q0 = p[0], q1 = p[1], q2 = p[2], q3 = p[3];
    float f[16] = {q0.x,q0.y,q0.z,q0.w, q1.x,q1.y,q1.z,q1.w,
                   q2.x,q2.y,q2.z,q2.w, q3.x,q3.y,q3.z,q3.w};
    double s = 0.0;
#pragma unroll
    for (int i = 0; i < 16; ++i) s += (double)f[i] * (double)f[i];
    double inv = 1.0 / sqrt(s + 1e-12);
    __attribute__((aligned(16))) unsigned short vp[3][16];
#pragma unroll
    for (int i = 0; i < 16; ++i)
      split3((float)((double)f[i] * inv), vp[0][i], vp[1][i], vp[2][i]);
#pragma unroll
    for (int pp = 0; pp < 3; ++pp) {
      size_t base = ((((size_t)hh * 128 + tl) * 3 + pp) * 16 + n) * 16;
      ((bf16x8*)(cfrag + base))[0] = ((bf16x8*)vp[pp])[0];
      ((bf16x8*)(cfrag + base))[1] = ((bf16x8*)vp[pp])[1];
    }
  } else if (tid >= 131072 && (tid & 7) == 0) {  // wsplit id = (tid-131072)>>3
    int id = (tid - 131072) >> 3;
    int o = id & 1, n = (id >> 1) & 15, c = (id >> 5) & 7, dg = id >> 8;
    __attribute__((aligned(16))) unsigned short vp[3][8];
#pragma unroll
    for (int j = 0; j < 8; ++j) {
      float v = W[c * 16384 + (dg * 16 + o * 8 + j) * 16 + n];
      split3(v, vp[0][j], vp[1][j], vp[2][j]);
    }
#pragma unroll
    for (int pp = 0; pp < 3; ++pp) {
      size_t base = ((((size_t)dg * 8 + c) * 3 + pp) * 16 + n) * 16 + o * 8;
      *(bf16x8*)(wfrag + base) = *(bf16x8*)vp[pp];
    }
  }
  if (bid >= 504) {                    // colsum, h = bid-504, threads t<256
    float (*red)[17] = (float(*)[17])smemF;
    int hh = bid - 504;
    if (t < 256) {
      int e = t & 15, part = t >> 4;
      const float* base = W + hh * 16384 + e;
      float s = 0.f;
      int d0 = part * 64;
      for (int i = 0; i < 64; ++i) s += base[(d0 + i) * 16];
      red[e][part] = s;
    }
    __syncthreads();
    if (t < 16) {
      float tt = 0.f;
#pragma unroll
      for (int p = 0; p < 16; ++p) tt += red[t][p];
      csum[hh * 16 + t] = tt;
    }
  }

  gbar(bar + 0, bar + 1, gridDim.x);

  // ================= Phase B: projection (R14 k_proj body) =================
  {
    const int r0 = bid * 16;
#pragma unroll
    for (int rr = 0; rr < 2; ++rr)
#pragma unroll
      for (int j4 = 0; j4 < 4; ++j4)
        stage16(x + (size_t)(r0 + 2 * w + rr) * 1024 + j4 * 256 + lane * 4,
                smemF + (2 * w + rr) * 1028 + j4 * 256);
    __syncthreads();

    f32x4 acc[8];
#pragma unroll
    for (int h = 0; h < 8; ++h) acc[h] = (f32x4){0.f, 0.f, 0.f, 0.f};
    float ps = 0.f;

#pragma unroll 4
    for (int dg2 = 0; dg2 < 8; ++dg2) {
      const int dg = w * 8 + dg2;
      const int dq = dg * 16 + oct * 8;
      float4 xa = *(const float4*)(smemF + n16 * 1028 + dq);
      float4 xb = *(const float4*)(smemF + n16 * 1028 + dq + 4);
      float xf[8] = {xa.x, xa.y, xa.z, xa.w, xb.x, xb.y, xb.z, xb.w};
      ps += ((xf[0] + xf[1]) + (xf[2] + xf[3])) +
            ((xf[4] + xf[5]) + (xf[6] + xf[7]));
      __attribute__((aligned(16))) unsigned short s1[8], s3[8];
#pragma unroll
      for (int j = 0; j < 8; ++j) {
        unsigned short hh, mm, ll;
        split3(xf[j], hh, mm, ll);
        s1[j] = qlt2 ? hh : mm;
        s3[j] = qlt2 ? hh : ll;
      }
      bf16x8 a1 = *(bf16x8*)s1;
      bf16x8 a3 = *(bf16x8*)s3;
#pragma unroll
      for (int hh = 0; hh < 8; ++hh) {
        size_t b0 = (((size_t)(dg * 8 + hh) * 3) * 16 + n16) * 16 + oct * 8;
        bf16x8 b1 = *(const bf16x8*)(wfrag + b0 + p1 * 256);
        bf16x8 b2 = *(const bf16x8*)(wfrag + b0 + p2 * 256);
        bf16x8 b3 = *(const bf16x8*)(wfrag + b0 + p3 * 256);
        acc[hh] = __builtin_amdgcn_mfma_f32_16x16x32_bf16(a1, b1, acc[hh], 0, 0, 0);
        acc[hh] = __builtin_amdgcn_mfma_f32_16x16x32_bf16(a1, b2, acc[hh], 0, 0, 0);
        acc[hh] = __builtin_amdgcn_mfma_f32_16x16x32_bf16(a3, b3, acc[hh], 0, 0, 0);
      }
    }

    __syncthreads();             // x reads done; smemF reused as reduce buffer
    float* sAcc = smemF;         // [4][64][33]

    if (w >= 4) {
#pragma unroll
      for (int hh = 0; hh < 8; ++hh)
#pragma unroll
        for (int r = 0; r < 4; ++r)
          sAcc[((w - 4) * 64 + lane) * 33 + hh * 4 + r] = acc[hh][r];
    }
    if (q < 2) sPs[w][q][n16] = ps;
    __syncthreads();
    if (w < 4) {
#pragma unroll
      for (int hh = 0; hh < 8; ++hh)
#pragma unroll
        for (int r = 0; r < 4; ++r)
          sAcc[(w * 64 + lane) * 33 + hh * 4 + r] =
              acc[hh][r] + sAcc[(w * 64 + lane) * 33 + hh * 4 + r];
    }
    if (t < 16) {
      float s = 0.f;
#pragma unroll
      for (int w2 = 0; w2 < 8; ++w2) s += sPs[w2][0][t] + sPs[w2][1][t];
      sMu[t] = s * (1.0f / 1024.0f);
    }
    __syncthreads();

    const int l = t & 63, head = t >> 6;
    const int lq = l >> 4, ln = l & 15;
    const float cs = csum[head * 16 + ln];
#pragma unroll
    for (int r = 0; r < 4; ++r) {
      const int f = head * 4 + r;
      float v = ((sAcc[(0 * 64 + l) * 33 + f] + sAcc[(1 * 64 + l) * 33 + f]) +
                 (sAcc[(2 * 64 + l) * 33 + f] + sAcc[(3 * 64 + l) * 33 + f]));
      const int row16 = lq * 4 + r;
      float tv = v - sMu[row16] * cs;
      unsigned short vh, vm, vl;
      split3(tv, vh, vm, vl);
      size_t base = ((size_t)head * 8192 + r0 + row16) * 16 + ln;
      ph[base] = vh; pm[base] = vm; pl[base] = vl;
    }
  }

  gbar(bar + 2, bar + 3, gridDim.x);

  // ================= Phase C: argmax (2 logical/block x 2 rounds) ==========
  {
    unsigned short* sB = (unsigned short*)smemF;   // 2 x 12288 shorts (48KB)
    const int wg = w >> 2, lw = w & 3;
    const int ehalf = oct * 8;
    const unsigned short* pa1 = qlt2 ? ph : pm;    // A1 = [h|m]
    const unsigned short* pa3 = qlt2 ? ph : pl;    // A3 = [h|l]
    unsigned short* sBw = sB + wg * 12288;

    for (int rep = 0; rep < 2; ++rep) {
      const int lid = rep * 1024 + bid * 2 + wg;   // 0..2047
      const int z = lid & 7, h = (lid >> 3) & 7, rg = lid >> 6;
      const int r0 = rg * 256 + lw * 64;

      __syncthreads();   // protect previous round's sB reads / phase B LDS
      const float* src =
          (const float*)(cfrag + ((size_t)(h * 128 + z * 16) * 3) * 256);
#pragma unroll
      for (int i = 0; i < 6; ++i)
        stage16(src + ((size_t)((i * 4 + lw) * 64) + lane) * 4,
                (float*)sBw + (i * 4 + lw) * 256);

      bf16x8 a1[4], a3[4];
#pragma unroll
      for (int rt = 0; rt < 4; ++rt) {
        size_t off = ((size_t)h * 8192 + r0 + rt * 16 + n16) * 16 + ehalf;
        a1[rt] = *(const bf16x8*)(pa1 + off);
        a3[rt] = *(const bf16x8*)(pa3 + off);
      }

      float best[4][4];
      int bidx[4][4];
#pragma unroll
      for (int rt = 0; rt < 4; ++rt)
#pragma unroll
        for (int r = 0; r < 4; ++r) {
          best[rt][r] = -3.402823466e38f; bidx[rt][r] = 0;
        }

      __syncthreads();

      for (int tile = 0; tile < 16; ++tile) {
        const int b0 = tile * 768 + n16 * 16 + ehalf;
        bf16x8 b1 = *(const bf16x8*)(sBw + b0 + p1 * 256);
        bf16x8 b2 = *(const bf16x8*)(sBw + b0 + p2 * 256);
        bf16x8 b3 = *(const bf16x8*)(sBw + b0 + p3 * 256);
        const int code = z * 256 + tile * 16 + n16;
#pragma unroll
        for (int rt = 0; rt < 4; ++rt) {
          f32x4 acc = {0.f, 0.f, 0.f, 0.f};
          acc = __builtin_amdgcn_mfma_f32_16x16x32_bf16(a1[rt], b1, acc, 0, 0, 0);
          acc = __builtin_amdgcn_mfma_f32_16x16x32_bf16(a1[rt], b2, acc, 0, 0, 0);
          acc = __builtin_amdgcn_mfma_f32_16x16x32_bf16(a3[rt], b3, acc, 0, 0, 0);
#pragma unroll
          for (int r = 0; r < 4; ++r)
            if (acc[r] > best[rt][r]) { best[rt][r] = acc[r]; bidx[rt][r] = code; }
        }
      }

#pragma unroll
      for (int off = 8; off >= 1; off >>= 1) {
#pragma unroll
        for (int rt = 0; rt < 4; ++rt)
#pragma unroll
          for (int r = 0; r < 4; ++r) {
            float ov = __shfl_xor(best[rt][r], off, 16);
            int oi = __shfl_xor(bidx[rt][r], off, 16);
            if (ov > best[rt][r] || (ov == best[rt][r] && oi < bidx[rt][r])) {
              best[rt][r] = ov; bidx[rt][r] = oi;
            }
          }
      }
      if (n16 == 0) {
#pragma unroll
        for (int rt = 0; rt < 4; ++rt)
#pragma unroll
          for (int r = 0; r < 4; ++r) {
            int row = r0 + rt * 16 + q * 4 + r;
            size_t o = (size_t)z * 65536 + (size_t)row * 8 + h;
            amv[o] = best[rt][r]; ami[o] = bidx[rt][r];
          }
      }
    }
  }

  gbar(bar + 4, bar + 5, gridDim.x);

  // ================= Phase D: merge the eight code-eighths =================
  if (tid < 65536) {
    float bv = amv[tid]; int bi = ami[tid];
#pragma unroll
    for (int z = 1; z < 8; ++z) {
      float v = amv[(size_t)z * 65536 + tid];
      if (v > bv) { bv = v; bi = ami[(size_t)z * 65536 + tid]; }
    }
    out[tid] = bi;
  }
}

extern "C" void kernel_launch(void* const* d_in, const int* in_sizes, int n_in,
                              void* d_out, int out_size, void* d_ws, size_t ws_size,
                              hipStream_t stream) {
  (void)in_sizes; (void)n_in; (void)out_size; (void)ws_size;
  const float* x  = (const float*)d_in[0];   // [4,2048,1024]
  const float* rp = (const float*)d_in[1];   // [8,1024,16]
  const float* cb = (const float*)d_in[2];   // [8,2048,16]
  int* out = (int*)d_out;                    // [8192,8] int32

  float* ws = (float*)d_ws;
  float*          csum  = ws;                              // 128
  float*          amv   = ws + 128;                        // 524288
  int*            ami   = (int*)(ws + 524416);             // 524288
  unsigned short* wfrag = (unsigned short*)(ws + 1048704); // 393216 sh
  unsigned short* cfrag = (unsigned short*)(ws + 1245312); // 786432 sh
  unsigned short* ph    = (unsigned short*)(ws + 1638528); // 1048576 sh each
  unsigned short* pm    = (unsigned short*)(ws + 2162816);
  unsigned short* pl    = (unsigned short*)(ws + 2687104);
  unsigned*       bar   = (unsigned*)(ws + 3211392);       // 6 uints

  hipMemsetAsync((void*)bar, 0, 6 * sizeof(unsigned), stream);
  hipLaunchKernelGGL(k_all, dim3(512), dim3(512), 0, stream,
                     x, rp, cb, out, csum, amv, ami, wfrag, cfrag,
                     ph, pm, pl, bar);
}

// Round 17
// 155.617 us; speedup vs baseline: 2.4060x; 2.4060x over previous
//
#include <hip/hip_runtime.h>
#include <math.h>

// b=4,n=2048 -> 8192 rows; d=1024; h=8; e=16; cs=2048. Output int32 [8192,8].
// argmax_c q.cbn_c == argmax_c ((x.W - mu*colsum(W)) . cbn_c). Codebook fp64-
// normalized. bf16 3-split MFMA path (verified R7/R10/R14): v = h+m+l (8+8+8
// mantissa bits, fp32 exponent range); v_p*v_c ~= hh + hm+mh + hl+mm+lh via 3
// quad-packed K=32 bf16 MFMAs. Frag-major B layouts (R9/R10).
//
// R17: the pipeline is ROW-LOCAL after prep -> fuse proj+argmax in one block
// with NO grid barrier (R16's manual barrier cost ~280us). Block = 16 rows:
// phase 1 = R14 proj (verbatim), epilogue -> 12KB LDS t-splits; phase 2 =
// wave w does head w over all 2048 codes, writes out directly. ph/pm/pl,
// amv/ami, amred, and 2 launches eliminated.

typedef short bf16x8 __attribute__((ext_vector_type(8)));
typedef float f32x4 __attribute__((ext_vector_type(4)));

__device__ __forceinline__ void stage16(const float* g, float* lds_base) {
  __builtin_amdgcn_global_load_lds(
      (const __attribute__((address_space(1))) void*)g,
      (__attribute__((address_space(3))) void*)lds_base, 16, 0, 0);
}

__device__ __forceinline__ unsigned short f2bf(float f) {
  unsigned u = __builtin_bit_cast(unsigned, f);
  unsigned r = (u + 0x7FFFu + ((u >> 16) & 1u)) >> 16;   // RNE
  return (unsigned short)r;
}
__device__ __forceinline__ float bf2f(unsigned short b) {
  return __builtin_bit_cast(float, (unsigned)b << 16);
}
__device__ __forceinline__ void split3(float v, unsigned short& h,
                                       unsigned short& m, unsigned short& l) {
  h = f2bf(v);
  float r = v - bf2f(h);
  m = f2bf(r);
  float r2 = r - bf2f(m);
  l = f2bf(r2);
}

// ---------------- K1: fused prep: cbnorm | colsum | wsplit (verified) -------
__global__ __launch_bounds__(256) void k_prep(const float* __restrict__ cb,
                                              const float* __restrict__ W,
                                              unsigned short* __restrict__ cfrag,
                                              float* __restrict__ csum,
                                              unsigned short* __restrict__ wfrag) {
  __shared__ float red[16][17];
  const int bid = blockIdx.x;
  const int t = threadIdx.x;
  if (bid < 64) {            // ---- cbnorm (fp64 normalize + bf16 3-split)
    int v = bid * 256 + t;
    int h = v >> 11, c = v & 2047, tl = c >> 4, n = c & 15;
    const float4* p = (const float4*)(cb + (size_t)v * 16);
    float4 q0 = p[0], q1 = p[1], q2 = p[2], q3 = p[3];
    float f[16] = {q0.x,q0.y,q0.z,q0.w, q1.x,q1.y,q1.z,q1.w,
                   q2.x,q2.y,q2.z,q2.w, q3.x,q3.y,q3.z,q3.w};
    double s = 0.0;
#pragma unroll
    for (int i = 0; i < 16; ++i) s += (double)f[i] * (double)f[i];
    double inv = 1.0 / sqrt(s + 1e-12);
    __attribute__((aligned(16))) unsigned short vp[3][16];
#pragma unroll
    for (int i = 0; i < 16; ++i)
      split3((float)((double)f[i] * inv), vp[0][i], vp[1][i], vp[2][i]);
#pragma unroll
    for (int pp = 0; pp < 3; ++pp) {
      size_t base = ((((size_t)h * 128 + tl) * 3 + pp) * 16 + n) * 16;
      ((bf16x8*)(cfrag + base))[0] = ((bf16x8*)vp[pp])[0];
      ((bf16x8*)(cfrag + base))[1] = ((bf16x8*)vp[pp])[1];
    }
  } else if (bid < 72) {     // ---- colsum
    int h = bid - 64;
    int e = t & 15, part = t >> 4;
    const float* base = W + h * 16384 + e;
    float s = 0.f;
    int d0 = part * 64;
    for (int i = 0; i < 64; ++i) s += base[(d0 + i) * 16];
    red[e][part] = s;
    __syncthreads();
    if (t < 16) {
      float tt = 0.f;
#pragma unroll
      for (int p = 0; p < 16; ++p) tt += red[t][p];
      csum[h * 16 + t] = tt;
    }
  } else {                   // ---- wsplit
    int id = (bid - 72) * 256 + t;
    int o = id & 1, n = (id >> 1) & 15, c = (id >> 5) & 7, dg = id >> 8;
    __attribute__((aligned(16))) unsigned short vp[3][8];
#pragma unroll
    for (int j = 0; j < 8; ++j) {
      float v = W[c * 16384 + (dg * 16 + o * 8 + j) * 16 + n];
      split3(v, vp[0][j], vp[1][j], vp[2][j]);
    }
#pragma unroll
    for (int pp = 0; pp < 3; ++pp) {
      size_t base = ((((size_t)dg * 8 + c) * 3 + pp) * 16 + n) * 16 + o * 8;
      *(bf16x8*)(wfrag + base) = *(bf16x8*)vp[pp];
    }
  }
}

// ---------------- K2: fused proj + argmax (row-local, no grid sync) ---------
// Grid 512 x 512 threads (2 blocks/CU, 66.9KB LDS). Block = 16 rows.
// Phase 1 (R14 proj body): x staged row-dense; wave w = d-groups [8w,8w+8);
// wave-pair LDS reduce; mu + csum; split3 -> tS[part][row][head][e] in LDS.
// Phase 2: wave w = head w, all 2048 codes (128 tiles); A-frags from tS; B
// streamed from frag-major cfrag (L2-hot); strict '>' + ascending per-lane
// codes + lexicographic shfl reduce = first-max; out written directly.
__global__ __launch_bounds__(512) void k_main(const float* __restrict__ x,
                                              const unsigned short* __restrict__ wfrag,
                                              const unsigned short* __restrict__ cfrag,
                                              const float* __restrict__ csum,
                                              int* __restrict__ out) {
  __shared__ __align__(16) float smemF[16 * 1028];   // 65792 B (multi-use)
  __shared__ float sPs[8][2][16];
  __shared__ float sMu[16];
  const int t = threadIdx.x;
  const int lane = t & 63, w = t >> 6;        // wave 0..7
  const int r0 = blockIdx.x * 16;
  const int q = lane >> 4, n16 = lane & 15, oct = q & 1;
  const bool qlt2 = (q < 2);
  const int p1 = qlt2 ? 0 : 1, p2 = qlt2 ? 1 : 0, p3 = qlt2 ? 2 : 0;
  const int ehalf = oct * 8;
  // t-split LDS block: [p(3)][row(16)][head(8)][e(16)] shorts, after sAcc.
  unsigned short* tS = (unsigned short*)((char*)smemF + 33792);  // 12288 B

  // ---------- Phase 1: projection (R14 body) ----------
#pragma unroll
  for (int rr = 0; rr < 2; ++rr)
#pragma unroll
    for (int j4 = 0; j4 < 4; ++j4)
      stage16(x + (size_t)(r0 + 2 * w + rr) * 1024 + j4 * 256 + lane * 4,
              smemF + (2 * w + rr) * 1028 + j4 * 256);
  __syncthreads();

  f32x4 acc[8];
#pragma unroll
  for (int h = 0; h < 8; ++h) acc[h] = (f32x4){0.f, 0.f, 0.f, 0.f};
  float ps = 0.f;

#pragma unroll 4
  for (int dg2 = 0; dg2 < 8; ++dg2) {
    const int dg = w * 8 + dg2;
    const int dq = dg * 16 + oct * 8;
    float4 xa = *(const float4*)(smemF + n16 * 1028 + dq);
    float4 xb = *(const float4*)(smemF + n16 * 1028 + dq + 4);
    float xf[8] = {xa.x, xa.y, xa.z, xa.w, xb.x, xb.y, xb.z, xb.w};
    ps += ((xf[0] + xf[1]) + (xf[2] + xf[3])) +
          ((xf[4] + xf[5]) + (xf[6] + xf[7]));
    __attribute__((aligned(16))) unsigned short s1[8], s3[8];
#pragma unroll
    for (int j = 0; j < 8; ++j) {
      unsigned short hh, mm, ll;
      split3(xf[j], hh, mm, ll);
      s1[j] = qlt2 ? hh : mm;
      s3[j] = qlt2 ? hh : ll;
    }
    bf16x8 a1 = *(bf16x8*)s1;
    bf16x8 a3 = *(bf16x8*)s3;
#pragma unroll
    for (int hh = 0; hh < 8; ++hh) {
      size_t b0 = (((size_t)(dg * 8 + hh) * 3) * 16 + n16) * 16 + oct * 8;
      bf16x8 b1 = *(const bf16x8*)(wfrag + b0 + p1 * 256);
      bf16x8 b2 = *(const bf16x8*)(wfrag + b0 + p2 * 256);
      bf16x8 b3 = *(const bf16x8*)(wfrag + b0 + p3 * 256);
      acc[hh] = __builtin_amdgcn_mfma_f32_16x16x32_bf16(a1, b1, acc[hh], 0, 0, 0);
      acc[hh] = __builtin_amdgcn_mfma_f32_16x16x32_bf16(a1, b2, acc[hh], 0, 0, 0);
      acc[hh] = __builtin_amdgcn_mfma_f32_16x16x32_bf16(a3, b3, acc[hh], 0, 0, 0);
    }
  }

  __syncthreads();             // x reads done; smemF front reused as sAcc
  float* sAcc = smemF;         // [4][64][33] = 33792 B (tS lives above it)

  if (w >= 4) {
#pragma unroll
    for (int hh = 0; hh < 8; ++hh)
#pragma unroll
      for (int r = 0; r < 4; ++r)
        sAcc[((w - 4) * 64 + lane) * 33 + hh * 4 + r] = acc[hh][r];
  }
  if (q < 2) sPs[w][q][n16] = ps;
  __syncthreads();
  if (w < 4) {
#pragma unroll
    for (int hh = 0; hh < 8; ++hh)
#pragma unroll
      for (int r = 0; r < 4; ++r)
        sAcc[(w * 64 + lane) * 33 + hh * 4 + r] =
            acc[hh][r] + sAcc[(w * 64 + lane) * 33 + hh * 4 + r];
  }
  if (t < 16) {
    float s = 0.f;
#pragma unroll
    for (int w2 = 0; w2 < 8; ++w2) s += sPs[w2][0][t] + sPs[w2][1][t];
    sMu[t] = s * (1.0f / 1024.0f);
  }
  __syncthreads();

  {  // epilogue: thread (head = t>>6, l = t&63) -> 4 cells, write tS (LDS)
    const int l = t & 63, head = t >> 6;
    const int lq = l >> 4, ln = l & 15;
    const float cs = csum[head * 16 + ln];
#pragma unroll
    for (int r = 0; r < 4; ++r) {
      const int f = head * 4 + r;
      float v = ((sAcc[(0 * 64 + l) * 33 + f] + sAcc[(1 * 64 + l) * 33 + f]) +
                 (sAcc[(2 * 64 + l) * 33 + f] + sAcc[(3 * 64 + l) * 33 + f]));
      const int row16 = lq * 4 + r;
      float tv = v - sMu[row16] * cs;
      unsigned short vh, vm, vl;
      split3(tv, vh, vm, vl);
      const int base = (row16 * 8 + head) * 16 + ln;
      tS[base] = vh;                 // p=0
      tS[2048 + base] = vm;          // p=1 (stride 16*8*16)
      tS[4096 + base] = vl;          // p=2
    }
  }
  __syncthreads();

  // ---------- Phase 2: argmax, wave w = head w, all 2048 codes ----------
  {
    const int h = w;
    const int pa3 = qlt2 ? 0 : 2;    // A3 = [h|l] (A-side part select)
    bf16x8 a1 = *(const bf16x8*)(tS + (p1 * 2048 + (n16 * 8 + h) * 16) + ehalf);
    bf16x8 a3 = *(const bf16x8*)(tS + (pa3 * 2048 + (n16 * 8 + h) * 16) + ehalf);

    float best[4];
    int   bidx[4];
#pragma unroll
    for (int r = 0; r < 4; ++r) { best[r] = -3.402823466e38f; bidx[r] = 0; }

#pragma unroll 4
    for (int tile = 0; tile < 128; ++tile) {
      size_t b0 = (((size_t)(h * 128 + tile) * 3) * 16 + n16) * 16 + ehalf;
      bf16x8 b1 = *(const bf16x8*)(cfrag + b0 + p1 * 256);
      bf16x8 b2 = *(const bf16x8*)(cfrag + b0 + p2 * 256);
      bf16x8 b3 = *(const bf16x8*)(cfrag + b0 + p3 * 256);
      f32x4 a = {0.f, 0.f, 0.f, 0.f};
      a = __builtin_amdgcn_mfma_f32_16x16x32_bf16(a1, b1, a, 0, 0, 0);
      a = __builtin_amdgcn_mfma_f32_16x16x32_bf16(a1, b2, a, 0, 0, 0);
      a = __builtin_amdgcn_mfma_f32_16x16x32_bf16(a3, b3, a, 0, 0, 0);
      const int code = tile * 16 + n16;
#pragma unroll
      for (int r = 0; r < 4; ++r)
        if (a[r] > best[r]) { best[r] = a[r]; bidx[r] = code; }
    }

#pragma unroll
    for (int off = 8; off >= 1; off >>= 1) {
#pragma unroll
      for (int r = 0; r < 4; ++r) {
        float ov = __shfl_xor(best[r], off, 16);
        int   oi = __shfl_xor(bidx[r], off, 16);
        if (ov > best[r] || (ov == best[r] && oi < bidx[r])) {
          best[r] = ov; bidx[r] = oi;
        }
      }
    }
    if (n16 == 0) {
#pragma unroll
      for (int r = 0; r < 4; ++r)
        out[(size_t)(r0 + q * 4 + r) * 8 + h] = bidx[r];
    }
  }
}

extern "C" void kernel_launch(void* const* d_in, const int* in_sizes, int n_in,
                              void* d_out, int out_size, void* d_ws, size_t ws_size,
                              hipStream_t stream) {
  (void)in_sizes; (void)n_in; (void)out_size; (void)ws_size;
  const float* x  = (const float*)d_in[0];   // [4,2048,1024]
  const float* rp = (const float*)d_in[1];   // [8,1024,16]
  const float* cb = (const float*)d_in[2];   // [8,2048,16]
  int* out = (int*)d_out;                    // [8192,8] int32

  float* ws = (float*)d_ws;
  float*          csum  = ws;                             // 128
  unsigned short* wfrag = (unsigned short*)(ws + 128);    // 393216 sh
  unsigned short* cfrag = (unsigned short*)(ws + 196736); // 786432 sh (~3.3MB)

  hipLaunchKernelGGL(k_prep, dim3(136), dim3(256), 0, stream,
                     cb, rp, cfrag, csum, wfrag);
  hipLaunchKernelGGL(k_main, dim3(512), dim3(512), 0, stream,
                     x, wfrag, cfrag, csum, out);
}